// Round 1
// baseline (451.321 us; speedup 1.0000x reference)
//
#include <hip/hip_runtime.h>

// Problem constants
constexpr int W   = 240;
constexpr int H   = 128;
constexpr int D   = 48;   // disparity bins
constexpr int G   = 40;   // groups
constexpr int CPG = 8;    // channels per group (320/40)
constexpr int CC  = 12;   // concat channels
constexpr int HW  = H * W;
constexpr int PAD = 48;        // left zero-pad so tgt[w-d] (w<d) reads zeros
constexpr int TROW = PAD + W;  // 288 floats per padded tgt row

// ---------------------------------------------------------------------------
// Kernel 1: groupwise-correlation volume, out channels [0, 40).
// One block per (g, h). LDS: ref[8][240], tgt[8][48+240] (zero-padded left).
// Each lane: fixed w4 (4 consecutive w), 12 consecutive d (per wave).
// Sliding 16-float tgt window in registers; statically-unrolled slices.
// ---------------------------------------------------------------------------
__global__ __launch_bounds__(256) void gwc_kernel(const float* __restrict__ ref,
                                                  const float* __restrict__ tgt,
                                                  float* __restrict__ out) {
  __shared__ float sref[CPG][W];
  __shared__ float stgt[CPG][TROW];

  const int g   = blockIdx.x >> 7;       // / H  (H = 128)
  const int h   = blockIdx.x & (H - 1);
  const int tid = threadIdx.x;

  // Zero the pad region: CPG * PAD floats = 384 = 96 float4 (16B-aligned: 288%4==0)
  for (int p = tid; p < CPG * (PAD / 4); p += 256) {
    int c = p / (PAD / 4);
    int i = p - c * (PAD / 4);
    *(float4*)&stgt[c][i * 4] = make_float4(0.f, 0.f, 0.f, 0.f);
  }
  // Load 8 ref rows + 8 tgt rows (coalesced float4; each HBM byte read once)
  const size_t rowbase = (size_t)(g * CPG) * HW + (size_t)h * W;
  for (int q = tid; q < CPG * (W / 4); q += 256) {
    int c  = q / (W / 4);
    int w4 = q - c * (W / 4);
    float4 rv = *(const float4*)&ref[rowbase + (size_t)c * HW + w4 * 4];
    float4 tv = *(const float4*)&tgt[rowbase + (size_t)c * HW + w4 * 4];
    *(float4*)&sref[c][w4 * 4]       = rv;
    *(float4*)&stgt[c][PAD + w4 * 4] = tv;
  }
  __syncthreads();

  const int lane = tid & 63;
  const int dq   = tid >> 6;          // wave id 0..3 -> d block of 12
  if (lane >= W / 4) return;          // 60 active lanes per wave
  const int w4 = lane;
  const int d0 = dq * 12;

  float4 acc[12];
#pragma unroll
  for (int j = 0; j < 12; ++j) acc[j] = make_float4(0.f, 0.f, 0.f, 0.f);

  // Window for d = d0+j starts at tgt element (4*w4 - d).  Aligned base:
  // base = 4*w4 - d0 - 12 (d0 % 4 == 0 -> base % 4 == 0).  Elements
  // base..base+15 cover all 12 windows; PAD=48 keeps base>=-48 in bounds.
  const int base = 4 * w4 - d0 - 12;
#pragma unroll
  for (int c = 0; c < CPG; ++c) {
    float4 r = *(const float4*)&sref[c][4 * w4];
    const float4* tp = (const float4*)&stgt[c][PAD + base];
    float tt[16];
    *(float4*)&tt[0]  = tp[0];
    *(float4*)&tt[4]  = tp[1];
    *(float4*)&tt[8]  = tp[2];
    *(float4*)&tt[12] = tp[3];
#pragma unroll
    for (int j = 0; j < 12; ++j) {   // d = d0 + j; window = tt[12-j .. 15-j]
      acc[j].x += r.x * tt[12 - j];
      acc[j].y += r.y * tt[13 - j];
      acc[j].z += r.z * tt[14 - j];
      acc[j].w += r.w * tt[15 - j];
    }
  }

  // out[((g*D + d)*H + h)*W + 4*w4]; mean over 8 channels = *0.125
  float* op = out + ((size_t)(g * D + d0) * H + h) * W + 4 * w4;
#pragma unroll
  for (int j = 0; j < 12; ++j) {
    float4 v = make_float4(acc[j].x * 0.125f, acc[j].y * 0.125f,
                           acc[j].z * 0.125f, acc[j].w * 0.125f);
    *(float4*)op = v;
    op += HW;
  }
}

// ---------------------------------------------------------------------------
// Kernel 2: concat volume, out channels [40, 64).
//   c2 in [0,12):  ref_concat[c2][h][w]   masked by (w >= d)
//   c2 in [12,24): tgt_concat[c2-12][h][w-d], zero for w < d
// One thread per output float4.  Sources (1.47 MB each) live in L2.
// ---------------------------------------------------------------------------
__global__ __launch_bounds__(256) void concat_kernel(const float* __restrict__ refc,
                                                     const float* __restrict__ tgtc,
                                                     float* __restrict__ out) {
  int idx = blockIdx.x * 256 + threadIdx.x;
  int w4 = idx % (W / 4);
  int r  = idx / (W / 4);
  int h  = r % H;  r /= H;
  int d  = r % D;
  int c2 = r / D;              // 0..23
  const int w0 = w4 * 4;

  float4 v;
  if (c2 < CC) {
    const float4 s = *(const float4*)&refc[(size_t)c2 * HW + h * W + w0];
    v.x = (w0 + 0 >= d) ? s.x : 0.f;
    v.y = (w0 + 1 >= d) ? s.y : 0.f;
    v.z = (w0 + 2 >= d) ? s.z : 0.f;
    v.w = (w0 + 3 >= d) ? s.w : 0.f;
  } else {
    const float* s = &tgtc[(size_t)(c2 - CC) * HW + h * W];
    v.x = (w0 + 0 >= d) ? s[w0 + 0 - d] : 0.f;
    v.y = (w0 + 1 >= d) ? s[w0 + 1 - d] : 0.f;
    v.z = (w0 + 2 >= d) ? s[w0 + 2 - d] : 0.f;
    v.w = (w0 + 3 >= d) ? s[w0 + 3 - d] : 0.f;
  }
  *(float4*)&out[(size_t)((G + c2) * D + d) * HW + (size_t)h * W + w0] = v;
}

extern "C" void kernel_launch(void* const* d_in, const int* in_sizes, int n_in,
                              void* d_out, int out_size, void* d_ws, size_t ws_size,
                              hipStream_t stream) {
  const float* ref_gwc    = (const float*)d_in[0];
  const float* tgt_gwc    = (const float*)d_in[1];
  const float* ref_concat = (const float*)d_in[2];
  const float* tgt_concat = (const float*)d_in[3];
  float* out = (float*)d_out;

  gwc_kernel<<<G * H, 256, 0, stream>>>(ref_gwc, tgt_gwc, out);

  const int n4 = 2 * CC * D * H * (W / 4);       // 8,847,360 float4s
  concat_kernel<<<n4 / 256, 256, 0, stream>>>(ref_concat, tgt_concat, out);
}

// Round 2
// 441.085 us; speedup vs baseline: 1.0232x; 1.0232x over previous
//
#include <hip/hip_runtime.h>

// Problem constants
constexpr int W   = 240;
constexpr int H   = 128;
constexpr int D   = 48;   // disparity bins
constexpr int G   = 40;   // groups
constexpr int CPG = 8;    // channels per group (320/40)
constexpr int CC  = 12;   // concat channels
constexpr int HW  = H * W;
constexpr int PAD = 48;        // left zero-pad so tgt[w-d] (w<d) reads zeros
constexpr int TROW = PAD + W;  // 288 floats per padded row

constexpr int NGWC = G * H;       // 5120 gwc blocks
constexpr int NCAT = 2 * CC * H;  // 3072 concat blocks (c2 0..23 x h)
// Interleave 5 gwc : 3 cat per group of 8 consecutive blockIdx (5120/3072 = 5/3)
constexpr int NGRID = NGWC + NCAT;  // 8192

__device__ __forceinline__ void nt_store4(float* p, float4 v) {
  __builtin_nontemporal_store(v.x, p + 0);
  __builtin_nontemporal_store(v.y, p + 1);
  __builtin_nontemporal_store(v.z, p + 2);
  __builtin_nontemporal_store(v.w, p + 3);
}

// ---------------------------------------------------------------------------
// Fused kernel.
// Type A (gwc): one block per (g, h). LDS ref[8][240] + tgt[8][288 padded].
//   lane = w4 (60 active), wave dq -> 12 consecutive d via one aligned
//   16-float register window per channel + static slices. mean/8 epilogue.
// Type B (cat): one block per (c2, h). LDS one padded row. Same lane/d
//   mapping; ref half = mask-select, tgt half = window slices. Pure copy.
// ---------------------------------------------------------------------------
__global__ __launch_bounds__(256) void fused_kernel(const float* __restrict__ ref,
                                                    const float* __restrict__ tgt,
                                                    const float* __restrict__ refc,
                                                    const float* __restrict__ tgtc,
                                                    float* __restrict__ out) {
  __shared__ float sref[CPG][W];
  __shared__ float stgt[CPG][TROW];

  const int bid = blockIdx.x;
  const int grp = bid >> 3;
  const int rr  = bid & 7;
  const int tid = threadIdx.x;

  const int lane = tid & 63;
  const int dq   = tid >> 6;   // 0..3 -> d block of 12
  const int w4   = lane;       // active if < 60
  const int d0   = dq * 12;

  if (rr < 5) {
    // ---------------- Type A: groupwise correlation ----------------
    const int aid = grp * 5 + rr;      // 0..5119
    const int g   = aid >> 7;
    const int h   = aid & (H - 1);

    for (int p = tid; p < CPG * (PAD / 4); p += 256) {
      int c = p / (PAD / 4);
      int i = p - c * (PAD / 4);
      *(float4*)&stgt[c][i * 4] = make_float4(0.f, 0.f, 0.f, 0.f);
    }
    const size_t rowbase = (size_t)(g * CPG) * HW + (size_t)h * W;
    for (int q = tid; q < CPG * (W / 4); q += 256) {
      int c  = q / (W / 4);
      int x4 = q - c * (W / 4);
      float4 rv = *(const float4*)&ref[rowbase + (size_t)c * HW + x4 * 4];
      float4 tv = *(const float4*)&tgt[rowbase + (size_t)c * HW + x4 * 4];
      *(float4*)&sref[c][x4 * 4]       = rv;
      *(float4*)&stgt[c][PAD + x4 * 4] = tv;
    }
    __syncthreads();
    if (w4 >= W / 4) return;

    float4 acc[12];
#pragma unroll
    for (int j = 0; j < 12; ++j) acc[j] = make_float4(0.f, 0.f, 0.f, 0.f);

    const int base = 4 * w4 - d0 - 12;   // aligned (d0 % 4 == 0)
#pragma unroll
    for (int c = 0; c < CPG; ++c) {
      float4 r = *(const float4*)&sref[c][4 * w4];
      const float4* tp = (const float4*)&stgt[c][PAD + base];
      float tt[16];
      *(float4*)&tt[0]  = tp[0];
      *(float4*)&tt[4]  = tp[1];
      *(float4*)&tt[8]  = tp[2];
      *(float4*)&tt[12] = tp[3];
#pragma unroll
      for (int j = 0; j < 12; ++j) {   // d = d0 + j; window = tt[12-j .. 15-j]
        acc[j].x += r.x * tt[12 - j];
        acc[j].y += r.y * tt[13 - j];
        acc[j].z += r.z * tt[14 - j];
        acc[j].w += r.w * tt[15 - j];
      }
    }

    float* op = out + ((size_t)(g * D + d0) * H + h) * W + 4 * w4;
#pragma unroll
    for (int j = 0; j < 12; ++j) {
      nt_store4(op, make_float4(acc[j].x * 0.125f, acc[j].y * 0.125f,
                                acc[j].z * 0.125f, acc[j].w * 0.125f));
      op += HW;
    }
  } else {
    // ---------------- Type B: concat volume ----------------
    const int cid = grp * 3 + (rr - 5);  // 0..3071
    const int c2  = cid >> 7;            // 0..23
    const int h   = cid & (H - 1);
    float* srow = &stgt[0][0];           // TROW floats

    if (tid < PAD / 4)
      *(float4*)&srow[tid * 4] = make_float4(0.f, 0.f, 0.f, 0.f);
    const bool is_ref = (c2 < CC);
    const float* src = is_ref ? (refc + (size_t)c2 * HW + (size_t)h * W)
                              : (tgtc + (size_t)(c2 - CC) * HW + (size_t)h * W);
    if (tid < W / 4)
      *(float4*)&srow[PAD + tid * 4] = *(const float4*)&src[tid * 4];
    __syncthreads();
    if (w4 >= W / 4) return;

    float* op = out + ((size_t)((G + c2) * D + d0) * H + h) * W + 4 * w4;
    if (is_ref) {
      const float4 rv = *(const float4*)&srow[PAD + 4 * w4];
      const int w0 = 4 * w4;
#pragma unroll
      for (int j = 0; j < 12; ++j) {
        const int d = d0 + j;
        float4 v;
        v.x = (w0 + 0 >= d) ? rv.x : 0.f;
        v.y = (w0 + 1 >= d) ? rv.y : 0.f;
        v.z = (w0 + 2 >= d) ? rv.z : 0.f;
        v.w = (w0 + 3 >= d) ? rv.w : 0.f;
        nt_store4(op, v);
        op += HW;
      }
    } else {
      const int base = 4 * w4 - d0 - 12;
      const float4* tp = (const float4*)&srow[PAD + base];
      float tt[16];
      *(float4*)&tt[0]  = tp[0];
      *(float4*)&tt[4]  = tp[1];
      *(float4*)&tt[8]  = tp[2];
      *(float4*)&tt[12] = tp[3];
#pragma unroll
      for (int j = 0; j < 12; ++j) {
        nt_store4(op, make_float4(tt[12 - j], tt[13 - j], tt[14 - j], tt[15 - j]));
        op += HW;
      }
    }
  }
}

extern "C" void kernel_launch(void* const* d_in, const int* in_sizes, int n_in,
                              void* d_out, int out_size, void* d_ws, size_t ws_size,
                              hipStream_t stream) {
  const float* ref_gwc    = (const float*)d_in[0];
  const float* tgt_gwc    = (const float*)d_in[1];
  const float* ref_concat = (const float*)d_in[2];
  const float* tgt_concat = (const float*)d_in[3];
  float* out = (float*)d_out;

  fused_kernel<<<NGRID, 256, 0, stream>>>(ref_gwc, tgt_gwc, ref_concat,
                                          tgt_concat, out);
}